// Round 4
// baseline (184.321 us; speedup 1.0000x reference)
//
#include <hip/hip_runtime.h>
#include <hip/hip_bf16.h>

// B=8, S=128, E=50, D=300, DE=50 — ALL I/O FLOAT32.
// out: node[307200] | edge[6553600].  ws (floats): R1[51200] | R2[51200]

typedef __bf16 bf16x8 __attribute__((ext_vector_type(8)));
typedef float f32x4 __attribute__((ext_vector_type(4)));

__device__ __forceinline__ unsigned short f2bf(float f) {
    __hip_bfloat16 h = __float2bfloat16(f);
    union { __hip_bfloat16 h; unsigned short u; } c; c.h = h; return c.u;
}

// ---------------- K1: msum + M@x + @Ww + LayerNorm + relu + R1/R2 --------------
// one block = 4 consecutive rows (b, i..i+3); 512 threads.
__global__ void __launch_bounds__(512) k_node(
    const float* __restrict__ wps,
    const float* __restrict__ wa,
    const float* __restrict__ x,
    const float* __restrict__ Ww,
    const float* __restrict__ Wb,
    const float* __restrict__ lna,
    const float* __restrict__ lnb,
    const float* __restrict__ Rw,
    const float* __restrict__ rb,
    float* __restrict__ node_out,
    float* __restrict__ R1, float* __restrict__ R2)
{
    __shared__ __align__(16) float stageF[12800];  // 51.2 KB; reused for R12 partials
    __shared__ float Ml[4][128];
    __shared__ float axm[4][304];                  // later reused as node buffer
    __shared__ float hl[4][304];
    __shared__ float diag[4][52];
    __shared__ float stats[8];
    int tid = threadIdx.x;
    int b = blockIdx.x >> 5;
    int ig = blockIdx.x & 31;
    int row0 = b * 128 + ig * 4;

    // ---- phase A: msum via coalesced staging (2 chunks of 2 rows) ----
    const float4* wb4 = (const float4*)(wps + (size_t)row0 * 6400);
    float4* s4 = (float4*)stageF;
    for (int c = 0; c < 2; ++c) {
        for (int i4 = tid; i4 < 3200; i4 += 512) s4[i4] = wb4[c * 3200 + i4];
        __syncthreads();
        if (tid < 256) {
            int rl = tid >> 7, j = tid & 127;
            const float* p = stageF + (rl * 128 + j) * 50;
            float s = 0.f;
#pragma unroll
            for (int e = 0; e < 50; e += 2) s += p[e] + p[e + 1];
            int r = c * 2 + rl;
            Ml[r][j] = s * (1.0f / 50.0f) + (((ig * 4 + r) == j) ? 1.0f : 0.0f);
        }
        __syncthreads();
    }
    if (tid < 200) {   // diag(wa) for the 4 rows
        int r = tid / 50, e = tid % 50;
        diag[r][e] = wa[(((size_t)(row0 + r)) * 128 + (ig * 4 + r)) * 50 + e];
    }

    // ---- phase B: Axm[r][d] = sum_j Ml[r][j] * x[b,j,d] ----
    if (tid < 300) {
        float a0 = 0.f, a1 = 0.f, a2 = 0.f, a3 = 0.f;
        const float* xp = x + (size_t)b * 38400 + tid;
#pragma unroll 4
        for (int j = 0; j < 128; ++j) {
            float xv = xp[j * 300];
            a0 += Ml[0][j] * xv; a1 += Ml[1][j] * xv;
            a2 += Ml[2][j] * xv; a3 += Ml[3][j] * xv;
        }
        axm[0][tid] = a0; axm[1][tid] = a1; axm[2][tid] = a2; axm[3][tid] = a3;
    }
    __syncthreads();

    // ---- phase C: h[r][d] = Wb[d] + sum_k axm[r][k] * Ww[k,d] ----
    if (tid < 300) {
        float wb = Wb[tid];
        float h0 = wb, h1 = wb, h2 = wb, h3 = wb;
        const float* wp = Ww + tid;
#pragma unroll 4
        for (int k = 0; k < 300; ++k) {
            float w = wp[k * 300];
            h0 += axm[0][k] * w; h1 += axm[1][k] * w;
            h2 += axm[2][k] * w; h3 += axm[3][k] * w;
        }
        hl[0][tid] = h0; hl[1][tid] = h1; hl[2][tid] = h2; hl[3][tid] = h3;
    }
    __syncthreads();

    // ---- phase D: LayerNorm (unbiased std + eps) + relu ----
    if (tid < 256) {
        int wv = tid >> 6, lane = tid & 63;
        float s1 = 0.f, s2 = 0.f;
        for (int dd = lane; dd < 300; dd += 64) {
            float v = hl[wv][dd]; s1 += v; s2 += v * v;
        }
        for (int off = 32; off > 0; off >>= 1) {
            s1 += __shfl_down(s1, off);
            s2 += __shfl_down(s2, off);
        }
        if (lane == 0) {
            float mean = s1 * (1.0f / 300.0f);
            float var = (s2 - 300.0f * mean * mean) * (1.0f / 299.0f);
            var = fmaxf(var, 0.0f);
            stats[wv * 2] = mean;
            stats[wv * 2 + 1] = 1.0f / (sqrtf(var) + 1e-6f);
        }
    }
    __syncthreads();
    if (tid < 300) {
        float la = lna[tid], lb = lnb[tid];
#pragma unroll
        for (int r = 0; r < 4; ++r) {
            float v = la * (hl[r][tid] - stats[r * 2]) * stats[r * 2 + 1] + lb;
            v = fmaxf(v, 0.0f);
            node_out[(size_t)(row0 + r) * 300 + tid] = v;
            axm[r][tid] = v;                 // reuse axm as node buffer
        }
    }
    __syncthreads();

    // ---- phase E: R1/R2 (row-invariant refine parts), split-K x8 ----
    if (tid < 400) {
        int k = tid % 50, p = tid / 50;
        float r1a[4] = {0.f, 0.f, 0.f, 0.f};
        float r2a[4] = {0.f, 0.f, 0.f, 0.f};
        int i0 = p * 44, i1 = (i0 + 44 < 350) ? i0 + 44 : 350;
        for (int idx = i0; idx < i1; ++idx) {
            float w1, w2;
            if (idx < 50) { w1 = Rw[(50 + idx) * 50 + k]; w2 = Rw[(100 + idx) * 50 + k]; }
            else { int d = idx - 50; w1 = Rw[(150 + d) * 50 + k]; w2 = Rw[(450 + d) * 50 + k]; }
#pragma unroll
            for (int r = 0; r < 4; ++r) {
                float m = (idx < 50) ? diag[r][idx] : axm[r][idx - 50];
                r1a[r] += m * w1; r2a[r] += m * w2;
            }
        }
#pragma unroll
        for (int r = 0; r < 4; ++r) {
            stageF[p * 200 + r * 50 + k] = r1a[r];
            stageF[1600 + p * 200 + r * 50 + k] = r2a[r];
        }
    }
    __syncthreads();
    if (tid < 200) {
        int r = tid / 50, k = tid % 50;
        float r1 = 0.f, r2 = rb[k];
#pragma unroll
        for (int p = 0; p < 8; ++p) {
            r1 += stageF[p * 200 + r * 50 + k];
            r2 += stageF[1600 + p * 200 + r * 50 + k];
        }
        R1[(size_t)(row0 + r) * 50 + k] = r1;
        R2[(size_t)(row0 + r) * 50 + k] = r2;
    }
}

// ---------------- K2: edge_out = wa·Rw[0:50] (MFMA) + R1[j] + R2[i] ------------
// one block per (b,i): 128x64x64(padded) bf16 MFMA; LDS-transposed fp32 epilogue.
__global__ void __launch_bounds__(256) k_edge(
    const float* __restrict__ wa,
    const float* __restrict__ Rw,
    const float* __restrict__ R1, const float* __restrict__ R2,
    float* __restrict__ eout)
{
    __shared__ __align__(16) unsigned char smem[27648];
    unsigned short* waA  = (unsigned short*)smem;            // 128*72 bf16 = 18432 B
    unsigned short* rwBT = (unsigned short*)(smem + 18432);  // 64*72 bf16  =  9216 B
    float* outF = (float*)smem;                              // alias: 6400 f = 25600 B
    int tid = threadIdx.x;
    int bi = blockIdx.x;       // b*128 + i
    int b = bi >> 7;

    for (int idx = tid; idx < 2304; idx += 256) ((unsigned int*)rwBT)[idx] = 0u;
    for (int idx = tid; idx < 1408; idx += 256) {            // zero waA pad e in [50,72)
        int j = idx / 11, c = idx % 11;
        *((unsigned int*)(waA + j * 72 + 50) + c) = 0u;
    }
    __syncthreads();

    const float2* wap = (const float2*)(wa + (size_t)bi * 6400);
    for (int idx = tid; idx < 3200; idx += 256) {
        float2 v = wap[idx];
        int f = idx * 2;
        int j = f / 50, e = f % 50;
        unsigned int pack = (unsigned int)f2bf(v.x) | ((unsigned int)f2bf(v.y) << 16);
        *(unsigned int*)(waA + j * 72 + e) = pack;
    }
    for (int idx = tid; idx < 2500; idx += 256) {            // transpose+cvt Rw[0:50][0:50]
        int e = idx / 50, kk = idx % 50;
        rwBT[kk * 72 + e] = f2bf(Rw[idx]);
    }
    __syncthreads();

    int lane = tid & 63, wv = tid >> 6;
    int q = lane >> 4, lr = lane & 15;
    f32x4 acc[2][4] = {};

#pragma unroll
    for (int ks = 0; ks < 2; ++ks) {
        int e0 = ks * 32 + q * 8;
        bf16x8 a0 = *(const bf16x8*)&waA[(wv * 32 + lr) * 72 + e0];
        bf16x8 a1 = *(const bf16x8*)&waA[(wv * 32 + 16 + lr) * 72 + e0];
#pragma unroll
        for (int nt = 0; nt < 4; ++nt) {
            bf16x8 bb = *(const bf16x8*)&rwBT[(nt * 16 + lr) * 72 + e0];
            acc[0][nt] = __builtin_amdgcn_mfma_f32_16x16x32_bf16(a0, bb, acc[0][nt], 0, 0, 0);
            acc[1][nt] = __builtin_amdgcn_mfma_f32_16x16x32_bf16(a1, bb, acc[1][nt], 0, 0, 0);
        }
    }
    __syncthreads();   // staging LDS dead; safe to alias as outF

    const float* r2p = R2 + (size_t)bi * 50;
#pragma unroll
    for (int nt = 0; nt < 4; ++nt) {
        int kk = nt * 16 + lr;
        if (kk < 50) {
            float r2v = r2p[kk];
#pragma unroll
            for (int mi = 0; mi < 2; ++mi) {
                int jbase = wv * 32 + mi * 16 + q * 4;
#pragma unroll
                for (int r = 0; r < 4; ++r)
                    outF[(jbase + r) * 50 + kk] = acc[mi][nt][r] + r2v;
            }
        }
    }
    __syncthreads();

    const float4* R1b = (const float4*)(R1 + (size_t)b * 6400);
    const float4* L4  = (const float4*)outF;
    float4* op4 = (float4*)(eout + (size_t)bi * 6400);
    for (int f4 = tid; f4 < 1600; f4 += 256) {
        float4 v = L4[f4];
        float4 r = R1b[f4];
        v.x += r.x; v.y += r.y; v.z += r.z; v.w += r.w;
        op4[f4] = v;
    }
}

extern "C" void kernel_launch(void* const* d_in, const int* in_sizes, int n_in,
                              void* d_out, int out_size, void* d_ws, size_t ws_size,
                              hipStream_t stream)
{
    const float* wps = (const float*)d_in[0];
    const float* wa  = (const float*)d_in[1];
    const float* x   = (const float*)d_in[2];
    // d_in[3] self_loop: identity on every channel, folded into k_node (+1 on diag)
    const float* Ww  = (const float*)d_in[4];
    const float* Wb  = (const float*)d_in[5];
    const float* lna = (const float*)d_in[6];
    const float* lnb = (const float*)d_in[7];
    const float* Rw  = (const float*)d_in[8];
    const float* rb  = (const float*)d_in[9];

    float* R1 = (float*)d_ws;            // 51200 floats
    float* R2 = ((float*)d_ws) + 51200;  // 51200 floats

    float* node_out = (float*)d_out;             // 307200 floats
    float* edge_out = node_out + 307200;         // 6553600 floats

    k_node<<<256, 512, 0, stream>>>(wps, wa, x, Ww, Wb, lna, lnb, Rw, rb,
                                    node_out, R1, R2);
    k_edge<<<1024, 256, 0, stream>>>(wa, Rw, R1, R2, edge_out);
}

// Round 5
// 160.260 us; speedup vs baseline: 1.1501x; 1.1501x over previous
//
#include <hip/hip_runtime.h>
#include <hip/hip_bf16.h>

// B=8, S=128, E=50, D=300, DE=50 — ALL I/O FLOAT32.
// out: node[307200] | edge[6553600].  ws (floats): R1[51200] | R2[51200]
// XW (=x@Ww, 307200 floats) is parked in the edge region of d_out and
// overwritten by k_edge afterwards.

typedef __bf16 bf16x8 __attribute__((ext_vector_type(8)));
typedef float f32x4 __attribute__((ext_vector_type(4)));

__device__ __forceinline__ unsigned short f2bf(float f) {
    __hip_bfloat16 h = __float2bfloat16(f);
    union { __hip_bfloat16 h; unsigned short u; } c; c.h = h; return c.u;
}

// ---------------- K0: XW[row,d] = sum_k x[row,k] * Ww[k,d] ---------------------
// one block per row (b*128+j); 320 threads; high occupancy hides K=300 chain.
__global__ void __launch_bounds__(320) k_xw(
    const float* __restrict__ x, const float* __restrict__ Ww,
    float* __restrict__ XW)
{
    __shared__ __align__(16) float xr[304];
    int tid = threadIdx.x;
    int row = blockIdx.x;                       // b*128 + j
    if (tid < 300) xr[tid] = x[(size_t)row * 300 + tid];
    else if (tid < 304) xr[tid] = 0.f;
    __syncthreads();
    if (tid < 300) {
        const float* wp = Ww + tid;
        const f32x4* x4 = (const f32x4*)xr;
        float acc = 0.f;
#pragma unroll 5
        for (int k4 = 0; k4 < 75; ++k4) {
            f32x4 xv = x4[k4];
            int k = k4 * 4;
            acc += xv[0] * wp[(k + 0) * 300];
            acc += xv[1] * wp[(k + 1) * 300];
            acc += xv[2] * wp[(k + 2) * 300];
            acc += xv[3] * wp[(k + 3) * 300];
        }
        XW[(size_t)row * 300 + tid] = acc;
    }
}

// ---------------- K1: msum + h=M@XW+Wb + LayerNorm + relu + R1/R2 --------------
// one block = 4 rows (b, i..i+3); 512 threads; branch-free unrolled phases.
__global__ void __launch_bounds__(512) k_node(
    const float* __restrict__ wps,
    const float* __restrict__ wa,
    const float* __restrict__ XW,
    const float* __restrict__ Wb,
    const float* __restrict__ lna,
    const float* __restrict__ lnb,
    const float* __restrict__ Rw,
    const float* __restrict__ rb,
    float* __restrict__ node_out,
    float* __restrict__ R1, float* __restrict__ R2)
{
    __shared__ __align__(16) float Ml[128][4];   // j-major: one b128 read per j
    __shared__ float hl[4][304];
    __shared__ float nodeL[4][304];
    __shared__ float diag[4][52];
    __shared__ float stats[8];
    __shared__ float part1[14][200];
    __shared__ float part2[14][200];
    int tid = threadIdx.x;
    int b = blockIdx.x >> 5;
    int ig = blockIdx.x & 31;
    int row0 = b * 128 + ig * 4;

    // ---- phase A: diag(wa) + msum (fully unrolled independent loads) ----
    if (tid < 200) {
        int r = tid / 50, e = tid % 50;
        diag[r][e] = wa[(((size_t)(row0 + r)) * 128 + (ig * 4 + r)) * 50 + e];
    }
    {
        int r = tid >> 7, j = tid & 127;
        const float2* p = (const float2*)(wps + ((size_t)(row0 + r)) * 6400 + j * 50);
        float s = 0.f;
#pragma unroll
        for (int n = 0; n < 25; ++n) { float2 v = p[n]; s += v.x + v.y; }
        Ml[j][r] = s * (1.0f / 50.0f) + (((ig * 4 + r) == j) ? 1.0f : 0.0f);
    }
    __syncthreads();

    // ---- phase B': h = M @ XW + Wb (t<300)  ||  E-diag partials (t>=312) ----
    if (tid < 300) {
        float wb = Wb[tid];
        float h0 = wb, h1 = wb, h2 = wb, h3 = wb;
        const float* xwp = XW + (size_t)b * 38400 + tid;
        const f32x4* M4 = (const f32x4*)Ml;
#pragma unroll 16
        for (int j = 0; j < 128; ++j) {
            float xv = xwp[j * 300];
            f32x4 m = M4[j];
            h0 += m[0] * xv; h1 += m[1] * xv; h2 += m[2] * xv; h3 += m[3] * xv;
        }
        hl[0][tid] = h0; hl[1][tid] = h1; hl[2][tid] = h2; hl[3][tid] = h3;
    } else if (tid >= 312) {
        int t = tid - 312, p = t / 50, k = t % 50;      // p in 0..3
        int e0 = p * 13, e1 = (e0 + 13 < 50) ? e0 + 13 : 50;
        float r1a[4] = {0.f, 0.f, 0.f, 0.f};
        float r2a[4] = {0.f, 0.f, 0.f, 0.f};
        for (int e = e0; e < e1; ++e) {
            float w1 = Rw[(50 + e) * 50 + k];
            float w2 = Rw[(100 + e) * 50 + k];
#pragma unroll
            for (int r = 0; r < 4; ++r) {
                r1a[r] += diag[r][e] * w1;
                r2a[r] += diag[r][e] * w2;
            }
        }
#pragma unroll
        for (int r = 0; r < 4; ++r) {
            part1[p][r * 50 + k] = r1a[r];
            part2[p][r * 50 + k] = r2a[r];
        }
    }
    __syncthreads();

    // ---- phase D: LayerNorm stats (unbiased std + eps) ----
    if (tid < 256) {
        int wv = tid >> 6, lane = tid & 63;
        float s1 = 0.f, s2 = 0.f;
        for (int dd = lane; dd < 300; dd += 64) {
            float v = hl[wv][dd]; s1 += v; s2 += v * v;
        }
        for (int off = 32; off > 0; off >>= 1) {
            s1 += __shfl_down(s1, off);
            s2 += __shfl_down(s2, off);
        }
        if (lane == 0) {
            float mean = s1 * (1.0f / 300.0f);
            float var = (s2 - 300.0f * mean * mean) * (1.0f / 299.0f);
            var = fmaxf(var, 0.0f);
            stats[wv * 2] = mean;
            stats[wv * 2 + 1] = 1.0f / (sqrtf(var) + 1e-6f);
        }
    }
    __syncthreads();

    // ---- node = relu(LN(h)) -> global + LDS ----
    if (tid < 300) {
        float la = lna[tid], lb = lnb[tid];
#pragma unroll
        for (int r = 0; r < 4; ++r) {
            float v = la * (hl[r][tid] - stats[r * 2]) * stats[r * 2 + 1] + lb;
            v = fmaxf(v, 0.0f);
            node_out[(size_t)(row0 + r) * 300 + tid] = v;
            nodeL[r][tid] = v;
        }
    }
    __syncthreads();

    // ---- phase E-node: split-K(10) node @ Rw partials ----
    if (tid < 500) {
        int p = tid / 50, k = tid % 50;      // p in 0..9
        int d0 = p * 30;
        float r1a[4] = {0.f, 0.f, 0.f, 0.f};
        float r2a[4] = {0.f, 0.f, 0.f, 0.f};
#pragma unroll 6
        for (int d = d0; d < d0 + 30; ++d) {
            float w1 = Rw[(150 + d) * 50 + k];
            float w2 = Rw[(450 + d) * 50 + k];
#pragma unroll
            for (int r = 0; r < 4; ++r) {
                r1a[r] += nodeL[r][d] * w1;
                r2a[r] += nodeL[r][d] * w2;
            }
        }
#pragma unroll
        for (int r = 0; r < 4; ++r) {
            part1[4 + p][r * 50 + k] = r1a[r];
            part2[4 + p][r * 50 + k] = r2a[r];
        }
    }
    __syncthreads();

    // ---- reduce partials -> R1/R2 ----
    if (tid < 200) {
        int r = tid / 50, k = tid % 50;
        float s1 = 0.f, s2 = rb[k];
#pragma unroll
        for (int p = 0; p < 14; ++p) {
            s1 += part1[p][r * 50 + k];
            s2 += part2[p][r * 50 + k];
        }
        R1[(size_t)(row0 + r) * 50 + k] = s1;
        R2[(size_t)(row0 + r) * 50 + k] = s2;
    }
}

// ---------------- K2: edge_out = wa·Rw[0:50] (MFMA) + R1[j] + R2[i] ------------
__global__ void __launch_bounds__(256) k_edge(
    const float* __restrict__ wa,
    const float* __restrict__ Rw,
    const float* __restrict__ R1, const float* __restrict__ R2,
    float* __restrict__ eout)
{
    __shared__ __align__(16) unsigned char smem[27648];
    unsigned short* waA  = (unsigned short*)smem;            // 128*72 bf16
    unsigned short* rwBT = (unsigned short*)(smem + 18432);  // 64*72 bf16
    float* outF = (float*)smem;                              // alias: 6400 floats
    int tid = threadIdx.x;
    int bi = blockIdx.x;       // b*128 + i
    int b = bi >> 7;

    for (int idx = tid; idx < 2304; idx += 256) ((unsigned int*)rwBT)[idx] = 0u;
    for (int idx = tid; idx < 1408; idx += 256) {            // zero waA pad e in [50,72)
        int j = idx / 11, c = idx % 11;
        *((unsigned int*)(waA + j * 72 + 50) + c) = 0u;
    }
    __syncthreads();

    const float2* wap = (const float2*)(wa + (size_t)bi * 6400);
    for (int idx = tid; idx < 3200; idx += 256) {
        float2 v = wap[idx];
        int f = idx * 2;
        int j = f / 50, e = f % 50;
        unsigned int pack = (unsigned int)f2bf(v.x) | ((unsigned int)f2bf(v.y) << 16);
        *(unsigned int*)(waA + j * 72 + e) = pack;
    }
    for (int idx = tid; idx < 2500; idx += 256) {            // transpose+cvt Rw[0:50][0:50]
        int e = idx / 50, kk = idx % 50;
        rwBT[kk * 72 + e] = f2bf(Rw[idx]);
    }
    __syncthreads();

    int lane = tid & 63, wv = tid >> 6;
    int q = lane >> 4, lr = lane & 15;
    f32x4 acc[2][4] = {};

#pragma unroll
    for (int ks = 0; ks < 2; ++ks) {
        int e0 = ks * 32 + q * 8;
        bf16x8 a0 = *(const bf16x8*)&waA[(wv * 32 + lr) * 72 + e0];
        bf16x8 a1 = *(const bf16x8*)&waA[(wv * 32 + 16 + lr) * 72 + e0];
#pragma unroll
        for (int nt = 0; nt < 4; ++nt) {
            bf16x8 bb = *(const bf16x8*)&rwBT[(nt * 16 + lr) * 72 + e0];
            acc[0][nt] = __builtin_amdgcn_mfma_f32_16x16x32_bf16(a0, bb, acc[0][nt], 0, 0, 0);
            acc[1][nt] = __builtin_amdgcn_mfma_f32_16x16x32_bf16(a1, bb, acc[1][nt], 0, 0, 0);
        }
    }
    __syncthreads();   // staging LDS dead; alias as outF

    const float* r2p = R2 + (size_t)bi * 50;
#pragma unroll
    for (int nt = 0; nt < 4; ++nt) {
        int kk = nt * 16 + lr;
        if (kk < 50) {
            float r2v = r2p[kk];
#pragma unroll
            for (int mi = 0; mi < 2; ++mi) {
                int jbase = wv * 32 + mi * 16 + q * 4;
#pragma unroll
                for (int r = 0; r < 4; ++r)
                    outF[(jbase + r) * 50 + kk] = acc[mi][nt][r] + r2v;
            }
        }
    }
    __syncthreads();

    const float4* R1b = (const float4*)(R1 + (size_t)b * 6400);
    const float4* L4  = (const float4*)outF;
    float4* op4 = (float4*)(eout + (size_t)bi * 6400);
    for (int f4 = tid; f4 < 1600; f4 += 256) {
        float4 v = L4[f4];
        float4 r = R1b[f4];
        v.x += r.x; v.y += r.y; v.z += r.z; v.w += r.w;
        op4[f4] = v;
    }
}

extern "C" void kernel_launch(void* const* d_in, const int* in_sizes, int n_in,
                              void* d_out, int out_size, void* d_ws, size_t ws_size,
                              hipStream_t stream)
{
    const float* wps = (const float*)d_in[0];
    const float* wa  = (const float*)d_in[1];
    const float* x   = (const float*)d_in[2];
    // d_in[3] self_loop: identity on every channel, folded into msum (+1 on diag)
    const float* Ww  = (const float*)d_in[4];
    const float* Wb  = (const float*)d_in[5];
    const float* lna = (const float*)d_in[6];
    const float* lnb = (const float*)d_in[7];
    const float* Rw  = (const float*)d_in[8];
    const float* rb  = (const float*)d_in[9];

    float* R1 = (float*)d_ws;            // 51200 floats
    float* R2 = ((float*)d_ws) + 51200;  // 51200 floats

    float* node_out = (float*)d_out;             // 307200 floats
    float* edge_out = node_out + 307200;         // 6553600 floats
    float* XW = edge_out;                        // scratch; overwritten by k_edge

    k_xw  <<<1024, 320, 0, stream>>>(x, Ww, XW);
    k_node<<<256, 512, 0, stream>>>(wps, wa, XW, Wb, lna, lnb, Rw, rb,
                                    node_out, R1, R2);
    k_edge<<<1024, 256, 0, stream>>>(wa, Rw, R1, R2, edge_out);
}